// Round 1
// 750.441 us; speedup vs baseline: 1.0381x; 1.0381x over previous
//
#include <hip/hip_runtime.h>

// Problem constants (match reference setup_inputs / module hyperparams)
#define BATCH 4
#define HGT   720
#define WID   1280
#define HW    (HGT * WID)           // 921600
#define NPIX  (BATCH * HW)          // 3686400
#define INV2S2 0.22222222222222222f // 1/(2*1.5^2)
#define INV_LAMBDA_E (255.0f / 30.0f)
#define THRESH 1e-6f
#define EPSV   1e-6f

// Gather-splat tiling: each lane owns one output pixel of a 16x16 tile and
// scans the extended source region. With the outlier cut at CUT, any staged
// source that can hit an output satisfies |tap - src| < CUT + 2, so margin
// GM = 4 suffices for CUT = 3.0 (offsets -4..4, 9x9 = 81 candidates vs the
// previous 13x13 = 169 at CUT = 4.9). Sources with |u| or |v| >= CUT
// (~0.54% of pixels for N(0,1) flow, ~20K px/frame) go to outlier_kernel.
#define GT   16
#define GM   4
#define GE   (GT + 2 * GM)   // 24
#define GEC  (GE * GE)       // 576 staged sources per block
#define CUT  3.0f

// ---------------------------------------------------------------------------
// Kernel 1: photometric error = mean_c |i1 - warp(i2, flow)|   -> err [N]
// ---------------------------------------------------------------------------
__global__ __launch_bounds__(256) void err_kernel(
    const float* __restrict__ i1, const float* __restrict__ i2,
    const float* __restrict__ flow, float* __restrict__ err) {
  int n = blockIdx.x * blockDim.x + threadIdx.x;
  if (n >= NPIX) return;
  int b = n / HW;
  int r = n - b * HW;
  int y = r / WID;
  int x = r - y * WID;

  float u = flow[(b * 2 + 0) * HW + r];
  float v = flow[(b * 2 + 1) * HW + r];
  float gx = fminf(fmaxf((float)x + u, 0.0f), (float)(WID - 1));
  float gy = fminf(fmaxf((float)y + v, 0.0f), (float)(HGT - 1));
  float x0f = floorf(gx), y0f = floorf(gy);
  int x0 = (int)x0f, y0 = (int)y0f;
  int x1 = min(x0 + 1, WID - 1), y1 = min(y0 + 1, HGT - 1);
  float wx = gx - x0f, wy = gy - y0f;
  float w00 = (1.0f - wx) * (1.0f - wy);
  float w01 = wx * (1.0f - wy);
  float w10 = (1.0f - wx) * wy;
  float w11 = wx * wy;
  int i00 = y0 * WID + x0, i01 = y0 * WID + x1;
  int i10 = y1 * WID + x0, i11 = y1 * WID + x1;

  const float* i2b = i2 + (size_t)b * 3 * HW;
  const float* i1b = i1 + (size_t)b * 3 * HW;
  float s = 0.0f;
#pragma unroll
  for (int c = 0; c < 3; ++c) {
    const float* p = i2b + c * HW;
    float wv = p[i00] * w00 + p[i01] * w01 + p[i10] * w10 + p[i11] * w11;
    s += fabsf(i1b[c * HW + r] - wv);
  }
  err[n] = s * (1.0f / 3.0f);
}

// ---------------------------------------------------------------------------
// Kernel 2: 3x3 zero-padded box filter of err, then fw = exp(-(e/LE)^2)
// ---------------------------------------------------------------------------
__global__ __launch_bounds__(256) void fw_kernel(
    const float* __restrict__ err, float* __restrict__ fw) {
  int n = blockIdx.x * blockDim.x + threadIdx.x;
  if (n >= NPIX) return;
  int b = n / HW;
  int r = n - b * HW;
  int y = r / WID;
  int x = r - y * WID;
  const float* e = err + (size_t)b * HW;
  float s = 0.0f;
#pragma unroll
  for (int dy = -1; dy <= 1; ++dy) {
    int yy = y + dy;
    if (yy < 0 || yy >= HGT) continue;
#pragma unroll
    for (int dx = -1; dx <= 1; ++dx) {
      int xx = x + dx;
      if (xx < 0 || xx >= WID) continue;
      s += e[yy * WID + xx];
    }
  }
  s *= (1.0f / 9.0f);
  float t = s * INV_LAMBDA_E;
  fw[n] = expf(-t * t);   // LAMBDA_V == 1
}

// ---------------------------------------------------------------------------
// Kernel 3: register-gather gaussian splat — ZERO atomics.
// Lane owns output (X,Y). Stage 24x24 source region (u,v SoA + premultiplied
// vals) into LDS, then scan 9x9 candidate offsets accumulating in regs.
// Hit predicate replicates the reference bit-exactly WITHOUT floor:
//   tx = (Xf + (ox-GM)) + u   (== fl(sx + u) exactly; sx integer-exact sum)
//   floor(tx)-X in [-2,1]  <=>  tx in [X-2, X+2)   (integer bounds, tx exact)
//   g = exp(-((tx-X)^2 + (ty-Y)^2) * INV2S2)       (subtractions exact)
// TAO_R truncation is dead (min in-window g = exp(-8/4.5) = 0.169 > 0.05).
// SoA u/v arrays at stride GE=24 give wave bank offsets {0,24,16,8} per
// row-group -> every bank exactly 2 lanes -> conflict-free ds_read_b32
// (the old float2 layout hit even banks only: 4-way conflicts, 2.35e7/disp).
// Outlier sources (|u| or |v| >= CUT) are staged as sentinel -> never hit;
// outlier_kernel adds them afterwards with global atomics.
// ---------------------------------------------------------------------------
__global__ __launch_bounds__(256) void splat_gather_kernel(
    const float* __restrict__ flow, const float* __restrict__ img,
    const float* __restrict__ fw, float* __restrict__ p,
    float* __restrict__ pw, float* __restrict__ rw) {
  __shared__ float su[GEC];      // u or 1e9 sentinel
  __shared__ float sv[GEC];      // v or 1e9 sentinel
  __shared__ float4 sval[GEC];   // (i0*fw, i1*fw, i2*fw, fw)

  const int b = blockIdx.z;
  const int tx0 = blockIdx.x * GT;
  const int ty0 = blockIdx.y * GT;
  const int ex0 = tx0 - GM;
  const int ey0 = ty0 - GM;
  const float* fu  = flow + (size_t)(b * 2 + 0) * HW;
  const float* fv  = flow + (size_t)(b * 2 + 1) * HW;
  const float* ib  = img + (size_t)b * 3 * HW;
  const float* fwb = fw + (size_t)b * HW;

  // ---- stage sources ----
  for (int i = threadIdx.x; i < GEC; i += 256) {
    int sly = i / GE, slx = i - sly * GE;
    int sx = ex0 + slx, sy = ey0 + sly;
    float uu = 1e9f, vv = 1e9f;
    float4 vl = make_float4(0.f, 0.f, 0.f, 0.f);
    if (sx >= 0 && sx < WID && sy >= 0 && sy < HGT) {
      int r = sy * WID + sx;
      float u = fu[r], v = fv[r];
      if (fabsf(u) < CUT && fabsf(v) < CUT) {   // complement of outlier_kernel
        uu = u; vv = v;
        float fwv = fwb[r];
        vl = make_float4(ib[r] * fwv, ib[HW + r] * fwv, ib[2 * HW + r] * fwv,
                         fwv);
      }
    }
    su[i] = uu;
    sv[i] = vv;
    sval[i] = vl;
  }
  __syncthreads();

  // ---- gather ----
  const int lx = threadIdx.x & 15;
  const int ly = threadIdx.x >> 4;
  const float Xf = (float)(tx0 + lx);
  const float Yf = (float)(ty0 + ly);
  const float Xlo = Xf - 2.0f, Xhi = Xf + 2.0f;
  const float Ylo = Yf - 2.0f, Yhi = Yf + 2.0f;

  // sxf[ox] = (float)sx for this lane's column at offset ox (integer-exact)
  float sxf[2 * GM + 1];
#pragma unroll
  for (int ox = 0; ox < 2 * GM + 1; ++ox) sxf[ox] = Xf + (float)(ox - GM);

  float a0 = 0.f, a1 = 0.f, a2 = 0.f, apw = 0.f, arw = 0.f;

  for (int oy = 0; oy < 2 * GM + 1; ++oy) {
    const int rowb = (ly + oy) * GE + lx;
    const float syf = Yf + (float)(oy - GM);   // (float)sy, exact
#pragma unroll
    for (int ox = 0; ox < 2 * GM + 1; ++ox) {
      float tx = sxf[ox] + su[rowb + ox];      // == fl(sx + u) exactly
      float ty = syf + sv[rowb + ox];
      if (tx >= Xlo && tx < Xhi && ty >= Ylo && ty < Yhi) {
        float ddx = tx - Xf;                   // exact
        float ddy = ty - Yf;
        float g = __expf(-(ddx * ddx + ddy * ddy) * INV2S2);
        float4 vl = sval[rowb + ox];
        a0 += vl.x * g;
        a1 += vl.y * g;
        a2 += vl.z * g;
        apw += vl.w * g;
        arw += g;
      }
    }
  }

  // ---- plain coalesced stores: sole owner of this output pixel ----
  const int gi = b * HW + (ty0 + ly) * WID + tx0 + lx;
  p[gi]            = a0;
  p[NPIX + gi]     = a1;
  p[2 * NPIX + gi] = a2;
  pw[gi]           = apw;
  rw[gi]           = arw;
}

// ---------------------------------------------------------------------------
// Kernel 3b: outlier splat — handles pixels with |flow| >= CUT (~20K/frame at
// CUT=3.0) via direct global atomics. Runs AFTER splat_gather (owner stores
// done). Separable exp differs from the fused-exp gather path by ~1 ulp.
// ---------------------------------------------------------------------------
__global__ __launch_bounds__(256) void outlier_kernel(
    const float* __restrict__ flow, const float* __restrict__ img,
    const float* __restrict__ fw, float* __restrict__ p,
    float* __restrict__ pw, float* __restrict__ rw) {
  int n = blockIdx.x * blockDim.x + threadIdx.x;
  if (n >= NPIX) return;
  int b = n / HW;
  int r = n - b * HW;
  float u = flow[(b * 2 + 0) * HW + r];
  float v = flow[(b * 2 + 1) * HW + r];
  if (fabsf(u) < CUT && fabsf(v) < CUT) return;  // complementary to gather

  int y = r / WID;
  int x = r - y * WID;
  float txf = (float)x + u, tyf = (float)y + v;
  float fx = floorf(txf), fy = floorf(tyf);
  int ixb = (int)fx, iyb = (int)fy;
  float fracx = txf - fx, fracy = tyf - fy;

  float gxv[4], gyv[4];
#pragma unroll
  for (int d = 0; d < 4; ++d) {
    float ddx = fracx - (float)(d - 1);
    gxv[d] = __expf(-ddx * ddx * INV2S2);
    float ddy = fracy - (float)(d - 1);
    gyv[d] = __expf(-ddy * ddy * INV2S2);
  }

  float fwv = fw[n];
  const float* ib = img + (size_t)b * 3 * HW;
  float s0 = ib[0 * HW + r] * fwv;
  float s1 = ib[1 * HW + r] * fwv;
  float s2 = ib[2 * HW + r] * fwv;

  int base = b * HW;
  for (int dy = 0; dy < 4; ++dy) {
    int iy = iyb + dy - 1;
    if (iy < 0 || iy >= HGT) continue;
    float gy = gyv[dy];
    for (int dx = 0; dx < 4; ++dx) {
      int ix = ixb + dx - 1;
      if (ix < 0 || ix >= WID) continue;
      float g = gxv[dx] * gy;
      int gi = base + iy * WID + ix;
      atomicAdd(p + gi, s0 * g);
      atomicAdd(p + NPIX + gi, s1 * g);
      atomicAdd(p + 2 * NPIX + gi, s2 * g);
      atomicAdd(pw + gi, fwv * g);
      atomicAdd(rw + gi, g);
    }
  }
}

// ---------------------------------------------------------------------------
// Kernel 4a: branch-1 accumulate: out = i1*w1 (write), den = w1 (write)
// ---------------------------------------------------------------------------
__global__ __launch_bounds__(256) void acc1_kernel(
    const float* __restrict__ p, const float* __restrict__ pw,
    const float* __restrict__ rw, float* __restrict__ out,
    float* __restrict__ den) {
  int n = blockIdx.x * blockDim.x + threadIdx.x;
  if (n >= NPIX) return;
  int b = n / HW;
  int r = n - b * HW;
  float pwv = pw[n], rwv = rw[n];
  float w = pwv / (rwv + THRESH);
  den[n] = w;
  float scale = w / (pwv + THRESH);
  int ob = b * 3 * HW + r;
  out[ob + 0 * HW] = p[n] * scale;
  out[ob + 1 * HW] = p[NPIX + n] * scale;
  out[ob + 2 * HW] = p[2 * NPIX + n] * scale;
}

// ---------------------------------------------------------------------------
// Kernel 4b: branch-2 accumulate + final blend:
//   out = (out + i2*w2) / (den + w2 + EPS)
// ---------------------------------------------------------------------------
__global__ __launch_bounds__(256) void acc2_kernel(
    const float* __restrict__ p, const float* __restrict__ pw,
    const float* __restrict__ rw, const float* __restrict__ den,
    float* __restrict__ out) {
  int n = blockIdx.x * blockDim.x + threadIdx.x;
  if (n >= NPIX) return;
  int b = n / HW;
  int r = n - b * HW;
  float pwv = pw[n], rwv = rw[n];
  float w = pwv / (rwv + THRESH);
  float scale = w / (pwv + THRESH);
  float d = den[n] + w + EPSV;
  float invd = 1.0f / d;
  int ob = b * 3 * HW + r;
  out[ob + 0 * HW] = (out[ob + 0 * HW] + p[n] * scale) * invd;
  out[ob + 1 * HW] = (out[ob + 1 * HW] + p[NPIX + n] * scale) * invd;
  out[ob + 2 * HW] = (out[ob + 2 * HW] + p[2 * NPIX + n] * scale) * invd;
}

// ---------------------------------------------------------------------------
// Launcher. Workspace layout (floats), 7N total = 103.2 MB:
//   [0, 3N)   p (3 planes); p[0] aliases err scratch (consumed before splat)
//   [3N, 4N)  pw   [4N, 5N)  rw   [5N, 6N)  fw   [6N, 7N)  den (w1)
// No memsets: gather stores fully initialize p/pw/rw before any read.
// ---------------------------------------------------------------------------
extern "C" void kernel_launch(void* const* d_in, const int* in_sizes, int n_in,
                              void* d_out, int out_size, void* d_ws,
                              size_t ws_size, hipStream_t stream) {
  const float* input1 = (const float*)d_in[0];
  const float* input2 = (const float*)d_in[1];
  const float* flow3  = (const float*)d_in[2];
  const float* flow4  = (const float*)d_in[3];
  float* out = (float*)d_out;

  float* ws  = (float*)d_ws;
  float* p   = ws;
  float* err = ws;
  float* pw  = ws + (size_t)3 * NPIX;
  float* rw  = ws + (size_t)4 * NPIX;
  float* fw  = ws + (size_t)5 * NPIX;
  float* den = ws + (size_t)6 * NPIX;

  const int threads = 256;
  const int blocks = (NPIX + threads - 1) / threads;
  dim3 sgrid(WID / GT, HGT / GT, BATCH);  // 80 x 45 x 4, all tiles full

  // ---- branch 1: warp input2 by flow3, compare to input1, splat input1 ----
  err_kernel<<<blocks, threads, 0, stream>>>(input1, input2, flow3, err);
  fw_kernel<<<blocks, threads, 0, stream>>>(err, fw);
  splat_gather_kernel<<<sgrid, threads, 0, stream>>>(flow3, input1, fw, p, pw, rw);
  outlier_kernel<<<blocks, threads, 0, stream>>>(flow3, input1, fw, p, pw, rw);
  acc1_kernel<<<blocks, threads, 0, stream>>>(p, pw, rw, out, den);

  // ---- branch 2: warp input1 by flow4, compare to input2, splat input2 ----
  err_kernel<<<blocks, threads, 0, stream>>>(input2, input1, flow4, err);
  fw_kernel<<<blocks, threads, 0, stream>>>(err, fw);
  splat_gather_kernel<<<sgrid, threads, 0, stream>>>(flow4, input2, fw, p, pw, rw);
  outlier_kernel<<<blocks, threads, 0, stream>>>(flow4, input2, fw, p, pw, rw);
  acc2_kernel<<<blocks, threads, 0, stream>>>(p, pw, rw, den, out);
}